// Round 1
// baseline (468.985 us; speedup 1.0000x reference)
//
#include <hip/hip_runtime.h>
#include <hip/hip_bf16.h>

#define HH 256   // hidden dim
#define HJ 128   // H/2
#define NB 32    // nodes per block in gate kernel
#define GG 512   // number of graphs (fixed by reference)

// ---------------- Kernel A: gating MLP -> per-node scalar s ----------------
// s[n] = tanh(x[n,:] @ W1 + b1) @ W2 + b2
__global__ __launch_bounds__(256) void gate_kernel(
    const float* __restrict__ x, const float* __restrict__ W1,
    const float* __restrict__ b1, const float* __restrict__ W2,
    const float* __restrict__ b2, float* __restrict__ s, int N) {
  __shared__ float xs[NB][HH];      // 32 KB x tile
  __shared__ float buf[NB][HJ];     // 16 KB partial-h combine
  __shared__ float partial[2][NB];  // per-wave scalar partials

  const int tid = threadIdx.x;
  const int j = tid & (HJ - 1);  // hidden unit 0..127
  const int kk = tid >> 7;       // k-half 0/1

  const float b1j = b1[j];
  const float w2j = W2[j];
  const float b2v = b2[0];

  const int base = blockIdx.x * NB;
  if (base >= N) return;
  const int nbc = min(NB, N - base);

  // stage x tile: 64 float4 per row, 4 rows in parallel
  {
    const int r0 = tid >> 6;
    const int kq = tid & 63;
    for (int r = r0; r < nbc; r += 4) {
      reinterpret_cast<float4*>(&xs[r][0])[kq] =
          reinterpret_cast<const float4*>(x + (size_t)(base + r) * HH)[kq];
    }
  }
  __syncthreads();

  float acc[NB];
#pragma unroll
  for (int nb = 0; nb < NB; ++nb) acc[nb] = 0.f;

  const float* w1p = W1 + (size_t)(kk * 128) * HJ + j;
  const int kbase = kk * 128;
#pragma unroll 2
  for (int k = 0; k < 128; k += 4) {
    const float wa = w1p[(k + 0) * HJ];
    const float wb = w1p[(k + 1) * HJ];
    const float wc = w1p[(k + 2) * HJ];
    const float wd = w1p[(k + 3) * HJ];
#pragma unroll
    for (int nb = 0; nb < NB; ++nb) {
      const float4 xv = *reinterpret_cast<const float4*>(&xs[nb][kbase + k]);
      acc[nb] = fmaf(xv.x, wa, acc[nb]);
      acc[nb] = fmaf(xv.y, wb, acc[nb]);
      acc[nb] = fmaf(xv.z, wc, acc[nb]);
      acc[nb] = fmaf(xv.w, wd, acc[nb]);
    }
  }

  if (kk == 1) {
#pragma unroll
    for (int nb = 0; nb < NB; ++nb) buf[nb][j] = acc[nb];
  }
  __syncthreads();

  if (kk == 0) {
    float c[NB];
#pragma unroll
    for (int nb = 0; nb < NB; ++nb) {
      const float h = acc[nb] + buf[nb][j] + b1j;
      c[nb] = tanhf(h) * w2j;
    }
    // 64-lane butterfly sum per wave (waves cover j 0..63 and 64..127)
    for (int off = 32; off > 0; off >>= 1) {
#pragma unroll
      for (int nb = 0; nb < NB; ++nb) c[nb] += __shfl_xor(c[nb], off, 64);
    }
    if ((tid & 63) == 0) {
      const int wv = tid >> 6;  // 0 or 1
#pragma unroll
      for (int nb = 0; nb < NB; ++nb) partial[wv][nb] = c[nb];
    }
  }
  __syncthreads();

  if (tid < nbc) {
    s[base + tid] = partial[0][tid] + partial[1][tid] + b2v;
  }
}

// ---------------- segment offsets from sorted batch ----------------
__global__ __launch_bounds__(256) void segstart_kernel(
    const int* __restrict__ batch, int* __restrict__ segstart, int N, int G) {
  const int n = blockIdx.x * 256 + threadIdx.x;
  if (n >= N) return;
  const int b = batch[n];
  const int p = (n == 0) ? -1 : batch[n - 1];
  for (int g = p + 1; g <= b; ++g) segstart[g] = n;
  if (n == N - 1) {
    for (int g = b + 1; g <= G; ++g) segstart[g] = N;
  }
}

// ---------------- Kernel C: per-graph softmax-weighted pool ----------------
// emb[g,h] = (sum_n e_n * x[n,h]) / (sum_n e_n),  e_n = exp(s_n - max_seg)
__global__ __launch_bounds__(256) void pool_kernel(
    const float* __restrict__ x, const float* __restrict__ s,
    const int* __restrict__ segstart, float* __restrict__ emb) {
  __shared__ float red[8];
  __shared__ float elds[256];
  const int g = blockIdx.x;
  const int tid = threadIdx.x;
  const int n0 = segstart[g];
  const int n1 = segstart[g + 1];

  // pass 1: segment max of s
  float mx = -3.402823466e38f;
  for (int n = n0 + tid; n < n1; n += 256) mx = fmaxf(mx, s[n]);
  for (int off = 32; off > 0; off >>= 1) mx = fmaxf(mx, __shfl_xor(mx, off, 64));
  if ((tid & 63) == 0) red[tid >> 6] = mx;
  __syncthreads();
  mx = fmaxf(fmaxf(red[0], red[1]), fmaxf(red[2], red[3]));

  // pass 2: accumulate e*x and e
  float acc = 0.f;
  float es = 0.f;
  for (int c0 = n0; c0 < n1; c0 += 256) {
    const int cn = min(256, n1 - c0);
    __syncthreads();
    if (tid < cn) {
      const float e = expf(s[c0 + tid] - mx);
      elds[tid] = e;
      es += e;
    }
    __syncthreads();
#pragma unroll 4
    for (int i = 0; i < cn; ++i) {
      acc = fmaf(elds[i], x[(size_t)(c0 + i) * HH + tid], acc);
    }
  }
  for (int off = 32; off > 0; off >>= 1) es += __shfl_xor(es, off, 64);
  if ((tid & 63) == 0) red[4 + (tid >> 6)] = es;
  __syncthreads();
  es = red[4] + red[5] + red[6] + red[7];
  const float inv = (es > 0.f) ? 1.f / es : 0.f;
  emb[(size_t)g * HH + tid] = acc * inv;
}

// ---------------- Kernel D: context = emb @ Wp + bp ----------------
__global__ __launch_bounds__(256) void proj_kernel(
    const float* __restrict__ emb, const float* __restrict__ Wp,
    const float* __restrict__ bp, float* __restrict__ ctx) {
  __shared__ float er[HH];
  const int g = blockIdx.x;
  const int tid = threadIdx.x;
  er[tid] = emb[(size_t)g * HH + tid];
  __syncthreads();
  float acc = bp[tid];
#pragma unroll 4
  for (int k = 0; k < HH; ++k) {
    acc = fmaf(er[k], Wp[(size_t)k * HH + tid], acc);
  }
  ctx[(size_t)g * HH + tid] = acc;
}

// ---------------- Kernel E: out[n,:] = ctx[batch[n],:] ----------------
__global__ __launch_bounds__(256) void gather_kernel(
    const float4* __restrict__ ctx4, const int* __restrict__ batch,
    float4* __restrict__ out4, long long total4) {
  const long long gid = (long long)blockIdx.x * 256 + threadIdx.x;
  if (gid >= total4) return;
  const int n = (int)(gid >> 6);   // 64 float4 per row
  const int q = (int)(gid & 63);
  out4[gid] = ctx4[(size_t)batch[n] * 64 + q];
}

extern "C" void kernel_launch(void* const* d_in, const int* in_sizes, int n_in,
                              void* d_out, int out_size, void* d_ws, size_t ws_size,
                              hipStream_t stream) {
  const float* x = (const float*)d_in[0];
  const int* batch = (const int*)d_in[1];
  const float* W1 = (const float*)d_in[2];
  const float* b1 = (const float*)d_in[3];
  const float* W2 = (const float*)d_in[4];
  const float* b2 = (const float*)d_in[5];
  const float* Wp = (const float*)d_in[6];
  const float* bp = (const float*)d_in[7];
  float* out = (float*)d_out;

  const int N = in_sizes[1];
  const int G = GG;

  // workspace layout (16B aligned chunks)
  char* w = (char*)d_ws;
  float* s = (float*)w;                       // N floats
  size_t off = ((size_t)N * 4 + 15) & ~15ull;
  int* segstart = (int*)(w + off);            // G+1 ints
  off += (((size_t)(G + 1) * 4 + 15) & ~15ull);
  float* emb = (float*)(w + off);             // G*H floats
  off += (size_t)G * HH * 4;
  float* ctx = (float*)(w + off);             // G*H floats

  // A: gate scores
  {
    dim3 grid((N + NB - 1) / NB);
    gate_kernel<<<grid, 256, 0, stream>>>(x, W1, b1, W2, b2, s, N);
  }
  // B: segment offsets
  {
    dim3 grid((N + 255) / 256);
    segstart_kernel<<<grid, 256, 0, stream>>>(batch, segstart, N, G);
  }
  // C: weighted pool
  pool_kernel<<<dim3(G), 256, 0, stream>>>(x, s, segstart, emb);
  // D: projection
  proj_kernel<<<dim3(G), 256, 0, stream>>>(emb, Wp, bp, ctx);
  // E: gather/broadcast to nodes
  {
    const long long total4 = (long long)N * (HH / 4);
    dim3 grid((unsigned)((total4 + 255) / 256));
    gather_kernel<<<grid, 256, 0, stream>>>((const float4*)ctx, batch,
                                            (float4*)out, total4);
  }
}

// Round 2
// 181.456 us; speedup vs baseline: 2.5846x; 2.5846x over previous
//
#include <hip/hip_runtime.h>
#include <hip/hip_bf16.h>

#define HH 256   // hidden dim
#define HJ 128   // H/2
#define GG 512   // number of graphs

typedef __attribute__((ext_vector_type(8))) short short8;
typedef __attribute__((ext_vector_type(4))) float f32x4;

static __device__ __forceinline__ short f2bf(float f) {
  // round-to-nearest-even fp32 -> bf16 (inputs are finite)
  unsigned u = __builtin_bit_cast(unsigned, f);
  unsigned r = (u + 0x7FFFu + ((u >> 16) & 1u)) >> 16;
  return (short)r;
}

// ---------------- Kernel 0: pre-fragment W1^T into MFMA A-operand order ----
// w1a[kt*8+jt][lane] = 8 bf16: A[m=j][k] with j = jt*16+(l&15), k = kt*32+(l>>4)*8+i
__global__ __launch_bounds__(64) void w1frag_kernel(
    const float* __restrict__ W1, short8* __restrict__ w1a) {
  const int l = threadIdx.x;
  const int kt = blockIdx.x >> 3;
  const int jt = blockIdx.x & 7;
  const int j = jt * 16 + (l & 15);
  const int kb = kt * 32 + (l >> 4) * 8;
  short8 v;
#pragma unroll
  for (int i = 0; i < 8; ++i) v[i] = f2bf(W1[(size_t)(kb + i) * HJ + j]);
  w1a[blockIdx.x * 64 + l] = v;
}

// ---------------- Kernel A: gating MLP via bf16 MFMA ----------------
// s[n] = tanh(x[n,:] @ W1 + b1) @ W2 + b2
// D = A*B with A = W1^T tile (j x k), B = x^T tile (k x node).
__global__ __launch_bounds__(512) void gate_mfma_kernel(
    const float* __restrict__ x, const short8* __restrict__ w1a,
    const float* __restrict__ b1, const float* __restrict__ W2,
    const float* __restrict__ b2, float* __restrict__ s, int N) {
  __shared__ short8 alds[4096];  // 64 KB: [kt(8)][jt(8)][lane(64)]
  const int tid = threadIdx.x;
  const int l = tid & 63;
  const int w = tid >> 6;  // wave 0..7

  // stage all A fragments (linear, coalesced, conflict-free)
#pragma unroll
  for (int i = 0; i < 8; ++i) alds[tid + i * 512] = w1a[tid + i * 512];

  const int node = blockIdx.x * 128 + w * 16 + (l & 15);
  const bool valid = node < N;
  const float* xp = x + (size_t)node * HH + (l >> 4) * 8;

  // B fragments: lane holds x[node][kt*32 + (l>>4)*8 + 0..7] as bf16
  short8 bfrag[8];
#pragma unroll
  for (int kt = 0; kt < 8; ++kt) {
    float4 f0 = make_float4(0.f, 0.f, 0.f, 0.f), f1 = f0;
    if (valid) {
      f0 = *reinterpret_cast<const float4*>(xp + kt * 32);
      f1 = *reinterpret_cast<const float4*>(xp + kt * 32 + 4);
    }
    short8 v;
    v[0] = f2bf(f0.x); v[1] = f2bf(f0.y); v[2] = f2bf(f0.z); v[3] = f2bf(f0.w);
    v[4] = f2bf(f1.x); v[5] = f2bf(f1.y); v[6] = f2bf(f1.z); v[7] = f2bf(f1.w);
    bfrag[kt] = v;
  }
  __syncthreads();

  f32x4 acc[8];
#pragma unroll
  for (int jt = 0; jt < 8; ++jt) acc[jt] = (f32x4)(0.f);

#pragma unroll
  for (int kt = 0; kt < 8; ++kt) {
#pragma unroll
    for (int jt = 0; jt < 8; ++jt) {
      acc[jt] = __builtin_amdgcn_mfma_f32_16x16x32_bf16(
          alds[(kt * 8 + jt) * 64 + l], bfrag[kt], acc[jt], 0, 0, 0);
    }
  }

  // epilogue: lane holds h[j][node] for j = jt*16 + (l>>4)*4 + r
  float sacc = 0.f;
  const int jb = (l >> 4) * 4;
#pragma unroll
  for (int jt = 0; jt < 8; ++jt) {
    const int j0 = jt * 16 + jb;
    const float4 bb = *reinterpret_cast<const float4*>(b1 + j0);
    const float4 ww = *reinterpret_cast<const float4*>(W2 + j0);
    sacc += tanhf(acc[jt][0] + bb.x) * ww.x;
    sacc += tanhf(acc[jt][1] + bb.y) * ww.y;
    sacc += tanhf(acc[jt][2] + bb.z) * ww.z;
    sacc += tanhf(acc[jt][3] + bb.w) * ww.w;
  }
  sacc += __shfl_xor(sacc, 16, 64);
  sacc += __shfl_xor(sacc, 32, 64);
  if ((l < 16) && valid) s[node] = sacc + b2[0];
}

// ---------------- segment offsets from sorted batch ----------------
__global__ __launch_bounds__(256) void segstart_kernel(
    const int* __restrict__ batch, int* __restrict__ segstart, int N, int G) {
  const int n = blockIdx.x * 256 + threadIdx.x;
  if (n >= N) return;
  const int b = batch[n];
  const int p = (n == 0) ? -1 : batch[n - 1];
  for (int g = p + 1; g <= b; ++g) segstart[g] = n;
  if (n == N - 1) {
    for (int g = b + 1; g <= G; ++g) segstart[g] = N;
  }
}

// ---------------- Kernel C: per-graph softmax-weighted pool ----------------
__global__ __launch_bounds__(256) void pool_kernel(
    const float* __restrict__ x, const float* __restrict__ s,
    const int* __restrict__ segstart, float* __restrict__ emb) {
  __shared__ float red[8];
  __shared__ float elds[256];
  const int g = blockIdx.x;
  const int tid = threadIdx.x;
  const int n0 = segstart[g];
  const int n1 = segstart[g + 1];

  float mx = -3.402823466e38f;
  for (int n = n0 + tid; n < n1; n += 256) mx = fmaxf(mx, s[n]);
  for (int off = 32; off > 0; off >>= 1) mx = fmaxf(mx, __shfl_xor(mx, off, 64));
  if ((tid & 63) == 0) red[tid >> 6] = mx;
  __syncthreads();
  mx = fmaxf(fmaxf(red[0], red[1]), fmaxf(red[2], red[3]));

  float acc = 0.f;
  float es = 0.f;
  for (int c0 = n0; c0 < n1; c0 += 256) {
    const int cn = min(256, n1 - c0);
    __syncthreads();
    if (tid < cn) {
      const float e = expf(s[c0 + tid] - mx);
      elds[tid] = e;
      es += e;
    }
    __syncthreads();
#pragma unroll 4
    for (int i = 0; i < cn; ++i) {
      acc = fmaf(elds[i], x[(size_t)(c0 + i) * HH + tid], acc);
    }
  }
  for (int off = 32; off > 0; off >>= 1) es += __shfl_xor(es, off, 64);
  if ((tid & 63) == 0) red[4 + (tid >> 6)] = es;
  __syncthreads();
  es = red[4] + red[5] + red[6] + red[7];
  const float inv = (es > 0.f) ? 1.f / es : 0.f;
  emb[(size_t)g * HH + tid] = acc * inv;
}

// ---------------- Kernel D: context = emb @ Wp + bp ----------------
__global__ __launch_bounds__(256) void proj_kernel(
    const float* __restrict__ emb, const float* __restrict__ Wp,
    const float* __restrict__ bp, float* __restrict__ ctx) {
  __shared__ float er[HH];
  const int g = blockIdx.x;
  const int tid = threadIdx.x;
  er[tid] = emb[(size_t)g * HH + tid];
  __syncthreads();
  float acc = bp[tid];
#pragma unroll 4
  for (int k = 0; k < HH; ++k) {
    acc = fmaf(er[k], Wp[(size_t)k * HH + tid], acc);
  }
  ctx[(size_t)g * HH + tid] = acc;
}

// ---------------- Kernel E: out[n,:] = ctx[batch[n],:] ----------------
__global__ __launch_bounds__(256) void gather_kernel(
    const float4* __restrict__ ctx4, const int* __restrict__ batch,
    float4* __restrict__ out4, long long total4) {
  const long long gid = (long long)blockIdx.x * 256 + threadIdx.x;
  if (gid >= total4) return;
  const int n = (int)(gid >> 6);  // 64 float4 per row
  const int q = (int)(gid & 63);
  out4[gid] = ctx4[(size_t)batch[n] * 64 + q];
}

extern "C" void kernel_launch(void* const* d_in, const int* in_sizes, int n_in,
                              void* d_out, int out_size, void* d_ws, size_t ws_size,
                              hipStream_t stream) {
  const float* x = (const float*)d_in[0];
  const int* batch = (const int*)d_in[1];
  const float* W1 = (const float*)d_in[2];
  const float* b1 = (const float*)d_in[3];
  const float* W2 = (const float*)d_in[4];
  const float* b2 = (const float*)d_in[5];
  const float* Wp = (const float*)d_in[6];
  const float* bp = (const float*)d_in[7];
  float* out = (float*)d_out;

  const int N = in_sizes[1];
  const int G = GG;

  // workspace layout (16B aligned chunks)
  char* wsp = (char*)d_ws;
  short8* w1a = (short8*)wsp;                 // 4096 short8 = 64 KB
  size_t off = 4096 * sizeof(short8);
  float* s = (float*)(wsp + off);             // N floats
  off += ((size_t)N * 4 + 15) & ~15ull;
  int* segstart = (int*)(wsp + off);          // G+1 ints
  off += (((size_t)(G + 1) * 4 + 15) & ~15ull);
  float* emb = (float*)(wsp + off);           // G*H floats
  off += (size_t)G * HH * 4;
  float* ctx = (float*)(wsp + off);           // G*H floats

  // 0: fragment W1
  w1frag_kernel<<<dim3(64), 64, 0, stream>>>(W1, w1a);
  // A: gate scores (MFMA)
  {
    dim3 grid((N + 127) / 128);
    gate_mfma_kernel<<<grid, 512, 0, stream>>>(x, w1a, b1, W2, b2, s, N);
  }
  // B: segment offsets
  {
    dim3 grid((N + 255) / 256);
    segstart_kernel<<<grid, 256, 0, stream>>>(batch, segstart, N, G);
  }
  // C: weighted pool
  pool_kernel<<<dim3(G), 256, 0, stream>>>(x, s, segstart, emb);
  // D: projection
  proj_kernel<<<dim3(G), 256, 0, stream>>>(emb, Wp, bp, ctx);
  // E: gather/broadcast to nodes
  {
    const long long total4 = (long long)N * (HH / 4);
    dim3 grid((unsigned)((total4 + 255) / 256));
    gather_kernel<<<grid, 256, 0, stream>>>((const float4*)ctx, batch,
                                            (float4*)out, total4);
  }
}